// Round 3
// baseline (196.725 us; speedup 1.0000x reference)
//
#include <hip/hip_runtime.h>
#include <stdint.h>

// Problem constants (fixed by reference setup_inputs)
#define NPOS 512   // N
#define NH   64    // H
#define NM   1024  // M
#define NB   256   // B
#define NM1  511   // N-1

typedef __attribute__((ext_vector_type(8)))  short bf16x8;
typedef __attribute__((ext_vector_type(16))) float f32x16;
typedef __attribute__((ext_vector_type(4)))  float f32x4;
typedef __attribute__((ext_vector_type(4)))  int   i32x4;

__device__ __forceinline__ unsigned short f2bf(float x) {
    unsigned u = __float_as_uint(x);
    u = (u + 0x7FFFu + ((u >> 16) & 1u)) >> 16;   // RNE
    return (unsigned short)u;
}
__device__ __forceinline__ int pack2(unsigned short a, unsigned short b) {
    return (int)a | ((int)b << 16);
}

// ---------------- K0: sequences fp32 -> bf16 (exact for +/-1); zero accum ----
__global__ __launch_bounds__(256, 4)
void k0_seq_bf16(const float* __restrict__ seq, unsigned short* __restrict__ seq_bf,
                 float* __restrict__ accum) {
    if (blockIdx.x == 0 && threadIdx.x == 0) accum[0] = 0.f;
    int idx = (blockIdx.x * 256 + threadIdx.x) * 4;
    f32x4 v = *(const f32x4*)(seq + idx);
    int2 o;
    o.x = pack2(f2bf(v.x), f2bf(v.y));
    o.y = pack2(f2bf(v.z), f2bf(v.w));
    *(int2*)(seq_bf + idx) = o;
}

// ---------------- K1a: Bn = softmax(B_logits, axis=-1), stored transposed ----
__global__ __launch_bounds__(64, 4)
void k1a_bnT(const float* __restrict__ Bl, float* __restrict__ BnT) {
    int h = blockIdx.x, l = threadIdx.x;
    float v[8]; float mx = -1e30f;
#pragma unroll
    for (int j = 0; j < 8; j++) { v[j] = Bl[h * NPOS + l + 64 * j]; mx = fmaxf(mx, v[j]); }
#pragma unroll
    for (int o = 32; o; o >>= 1) mx = fmaxf(mx, __shfl_xor(mx, o));
    float s = 0.f;
#pragma unroll
    for (int j = 0; j < 8; j++) { v[j] = __expf(v[j] - mx); s += v[j]; }
#pragma unroll
    for (int o = 32; o; o >>= 1) s += __shfl_xor(s, o);
    float r = 1.0f / s;
#pragma unroll
    for (int j = 0; j < 8; j++) BnT[(l + 64 * j) * NH + h] = v[j] * r;
}

// ---------------- K1b: phi_mu[m,h] = sum_n Bn[h,n]*memory[m,n] -> bf16 -------
// 4 independent accumulators: break the serially-dependent fma/load chain.
__global__ __launch_bounds__(256, 4)
void k1b_phimu(const float* __restrict__ BnT, const float* __restrict__ mem,
               unsigned short* __restrict__ phimu) {
    int m = blockIdx.x, t = threadIdx.x;
    __shared__ float mrow[NPOS];
    __shared__ float part[256];
    if (t < 128) *(f32x4*)(mrow + t * 4) = *(const f32x4*)(mem + m * NPOS + t * 4);
    __syncthreads();
    int h = t & 63, seg = t >> 6;
    float a0 = 0.f, a1 = 0.f, a2 = 0.f, a3 = 0.f;
    const float* bp = BnT + seg * 128 * NH + h;
    const float* mr = mrow + seg * 128;
#pragma unroll 8
    for (int nn = 0; nn < 128; nn += 4) {
        a0 = fmaf(bp[(nn + 0) * NH], mr[nn + 0], a0);
        a1 = fmaf(bp[(nn + 1) * NH], mr[nn + 1], a1);
        a2 = fmaf(bp[(nn + 2) * NH], mr[nn + 2], a2);
        a3 = fmaf(bp[(nn + 3) * NH], mr[nn + 3], a3);
    }
    part[t] = (a0 + a1) + (a2 + a3);
    __syncthreads();
    if (t < 64) {
        float a = part[t] + part[t + 64] + part[t + 128] + part[t + 192];
        phimu[m * NH + t] = f2bf(a);
    }
}

// ---------------- K1c: plusT[n][m] via LDS tile transpose (coalesced) --------
// grid 128: blockIdx = mt*8 + nt; 64x64 tile.
__global__ __launch_bounds__(256, 4)
void k1c_plusT(const float* __restrict__ mem, float* __restrict__ plusT) {
    __shared__ float sT[64][65];
    const int mt = blockIdx.x >> 3, nt = blockIdx.x & 7;
    const int t = threadIdx.x, rr = t >> 2, cc = t & 3;
    const float* src = mem + (size_t)(mt * 64 + rr) * NPOS + nt * 64 + cc * 16;
#pragma unroll
    for (int j = 0; j < 4; j++) {
        f32x4 v = *(const f32x4*)(src + j * 4);
        sT[rr][cc * 16 + j * 4 + 0] = (v.x > 0.f) ? 1.f : 0.f;
        sT[rr][cc * 16 + j * 4 + 1] = (v.y > 0.f) ? 1.f : 0.f;
        sT[rr][cc * 16 + j * 4 + 2] = (v.z > 0.f) ? 1.f : 0.f;
        sT[rr][cc * 16 + j * 4 + 3] = (v.w > 0.f) ? 1.f : 0.f;
    }
    __syncthreads();
    float* dst = plusT + (size_t)(nt * 64 + rr) * NM + mt * 64 + cc * 16;
#pragma unroll
    for (int j = 0; j < 4; j++) {
        f32x4 o;
        o.x = sT[cc * 16 + j * 4 + 0][rr];
        o.y = sT[cc * 16 + j * 4 + 1][rr];
        o.z = sT[cc * 16 + j * 4 + 2][rr];
        o.w = sT[cc * 16 + j * 4 + 3][rr];
        *(f32x4*)(dst + j * 4) = o;
    }
}

// ---------------- K2: fused masked-softmax + GEMM -> hat_phi (n,b,h) bf16 ----
// grid 511 (one block per n): A_logits read ONCE. Tile 256b x 64h, 4 waves.
// Pipelined: exp/stage(k) from regs | barrier | prefetch(k+1) + MFMA(k) | barrier.
__global__ __launch_bounds__(256, 2)
void k2_hatphi(const float* __restrict__ Al, const unsigned short* __restrict__ seq_bf,
               unsigned short* __restrict__ hatphi) {
    __shared__ __align__(16) unsigned short s_lds[256 * 72];  // S tile / out tile
    __shared__ __align__(16) unsigned short e_lds[64 * 72];   // exp(A) tile
    __shared__ float z_lds[64];                               // row sums Z[h]

    const int t = threadIdx.x;
    const int n = NM1 - (int)blockIdx.x;          // n in 1..511, big n first
    const int ksteps = (n + 63) >> 6;
    const int wv = t >> 6, lane = t & 63, half = lane >> 5, r = lane & 31;

    if (t < 64) z_lds[t] = 0.f;

    const int eh = t >> 2, ei = (t & 3) * 16;
    const float* arow = Al + ((size_t)n * NH + eh) * NPOS + ei;
    const unsigned short* srcS = seq_bf + (size_t)t * NPOS;

    f32x16 acc00, acc01, acc10, acc11;
#pragma unroll
    for (int i = 0; i < 16; i++) { acc00[i] = 0.f; acc01[i] = 0.f; acc10[i] = 0.f; acc11[i] = 0.f; }

    // prologue loads for k=0
    f32x4 ea[4]; i32x4 sa[8];
#pragma unroll
    for (int g = 0; g < 4; g++) ea[g] = *(const f32x4*)(arow + g * 4);
#pragma unroll
    for (int c = 0; c < 8; c++) sa[c] = *(const i32x4*)(srcS + c * 8);
    __syncthreads();   // z_lds init visible

    for (int kk = 0; kk < ksteps; kk++) {
        const int k0 = kk * 64;
        // exp + stage E tile from regs
        {
            float zp = 0.f;
            unsigned short* ep = e_lds + eh * 72 + ei;
#pragma unroll
            for (int g = 0; g < 4; g++) {
                int i0 = k0 + ei + g * 4;
                float e0 = (i0 + 0 < n) ? __expf(ea[g].x) : 0.f;
                float e1 = (i0 + 1 < n) ? __expf(ea[g].y) : 0.f;
                float e2 = (i0 + 2 < n) ? __expf(ea[g].z) : 0.f;
                float e3 = (i0 + 3 < n) ? __expf(ea[g].w) : 0.f;
                zp += (e0 + e1) + (e2 + e3);
                int2 o; o.x = pack2(f2bf(e0), f2bf(e1)); o.y = pack2(f2bf(e2), f2bf(e3));
                *(int2*)(ep + g * 4) = o;
            }
            zp += __shfl_xor(zp, 1);
            zp += __shfl_xor(zp, 2);
            if ((t & 3) == 0) z_lds[eh] += zp;
        }
        // stage S tile from regs (thread t owns row t, 64 bf16/kstep)
        {
            unsigned short* dp = s_lds + t * 72;
#pragma unroll
            for (int c = 0; c < 8; c++) *(i32x4*)(dp + c * 8) = sa[c];
        }
        __syncthreads();
        // prefetch k+1 (in flight during MFMA phase)
        if (kk + 1 < ksteps) {
#pragma unroll
            for (int g = 0; g < 4; g++) ea[g] = *(const f32x4*)(arow + k0 + 64 + g * 4);
#pragma unroll
            for (int c = 0; c < 8; c++) sa[c] = *(const i32x4*)(srcS + k0 + 64 + c * 8);
        }
        // MFMA: D[b][h] += S[b,i] * E[h,i]
        {
            const unsigned short* sA0 = s_lds + (wv * 64 + r) * 72;
            const unsigned short* sA1 = sA0 + 32 * 72;
            const unsigned short* sB0 = e_lds + r * 72;
            const unsigned short* sB1 = sB0 + 32 * 72;
#pragma unroll
            for (int kq = 0; kq < 4; kq++) {
                const int ko = kq * 16 + half * 8;
                bf16x8 A0 = *(const bf16x8*)(sA0 + ko);
                bf16x8 A1 = *(const bf16x8*)(sA1 + ko);
                bf16x8 B0 = *(const bf16x8*)(sB0 + ko);
                bf16x8 B1 = *(const bf16x8*)(sB1 + ko);
                acc00 = __builtin_amdgcn_mfma_f32_32x32x16_bf16(A0, B0, acc00, 0, 0, 0);
                acc01 = __builtin_amdgcn_mfma_f32_32x32x16_bf16(A0, B1, acc01, 0, 0, 0);
                acc10 = __builtin_amdgcn_mfma_f32_32x32x16_bf16(A1, B0, acc10, 0, 0, 0);
                acc11 = __builtin_amdgcn_mfma_f32_32x32x16_bf16(A1, B1, acc11, 0, 0, 0);
            }
        }
        __syncthreads();
    }
    // epilogue: scale by 1/Z[h], transpose through LDS, coalesced store (n,b,h)
    float rz0 = 1.0f / z_lds[r];
    float rz1 = 1.0f / z_lds[32 + r];
    unsigned short* o_lds = s_lds;  // safe: last barrier fenced MFMA reads
#pragma unroll
    for (int reg = 0; reg < 16; reg++) {
        int row = (reg & 3) + 8 * (reg >> 2) + 4 * half;
        o_lds[(wv * 64 + row) * 72 + r]            = f2bf(acc00[reg] * rz0);
        o_lds[(wv * 64 + row) * 72 + 32 + r]       = f2bf(acc01[reg] * rz1);
        o_lds[(wv * 64 + 32 + row) * 72 + r]       = f2bf(acc10[reg] * rz0);
        o_lds[(wv * 64 + 32 + row) * 72 + 32 + r]  = f2bf(acc11[reg] * rz1);
    }
    __syncthreads();
    {
        unsigned short* gp = hatphi + (size_t)(n - 1) * NB * NH + (size_t)t * NH;
        const unsigned short* lp = o_lds + t * 72;
#pragma unroll
        for (int c = 0; c < 8; c++) *(i32x4*)(gp + c * 8) = *(const i32x4*)(lp + c * 8);
    }
}

// ---------------- K3: retrieval softmax (no-max streaming) + BCE -------------
// grid (511, 2), block 256 = 4 waves. Each wave owns a 32-b strip (q = 16 VGPRs)
// and loops all 32 m-tiles, software-pipelined: MFMA(tile i+1) issues before
// the exp/accumulate of tile i; p-frags loaded one tile ahead.
__global__ __launch_bounds__(256, 4)
void k3_retrieve(const unsigned short* __restrict__ hatphi,
                 const unsigned short* __restrict__ phimu,
                 const float* __restrict__ plusT,
                 const float* __restrict__ seq,
                 float* __restrict__ accum) {
    const int n = (int)blockIdx.x + 1;
    const int bblk = (int)blockIdx.y;           // 128 b per block
    const int t = threadIdx.x, wv = t >> 6, lane = t & 63, half = lane >> 5, r = lane & 31;
    const int bstrip = bblk * 128 + wv * 32;

    __shared__ float s_plus[NM];
    __shared__ float dsum[4][32];
    __shared__ float nsum[4][32];
    __shared__ float wsum[2];

    // stage plus row (one dwordx4 per thread)
    *(f32x4*)(s_plus + t * 4) = *(const f32x4*)(plusT + n * NM + t * 4);

    // q fragments for this wave's 32 b (held all kernel)
    bf16x8 q[4];
    {
        const unsigned short* qb = hatphi + (size_t)(n - 1) * NB * NH + (bstrip + r) * NH + half * 8;
#pragma unroll
        for (int kq = 0; kq < 4; kq++) q[kq] = *(const bf16x8*)(qb + kq * 16);
    }
    // p fragments, tile 0
    bf16x8 p[4];
    {
        const unsigned short* pb = phimu + r * NH + half * 8;
#pragma unroll
        for (int kq = 0; kq < 4; kq++) p[kq] = *(const bf16x8*)(pb + kq * 16);
    }
    __syncthreads();   // s_plus visible

    f32x16 a_cur;
#pragma unroll
    for (int i = 0; i < 16; i++) a_cur[i] = 0.f;
#pragma unroll
    for (int kq = 0; kq < 4; kq++)
        a_cur = __builtin_amdgcn_mfma_f32_32x32x16_bf16(p[kq], q[kq], a_cur, 0, 0, 0);
    // load tile 1
    {
        const unsigned short* pb = phimu + (32 + r) * NH + half * 8;
#pragma unroll
        for (int kq = 0; kq < 4; kq++) p[kq] = *(const bf16x8*)(pb + kq * 16);
    }

    f32x4 den = {0.f,0.f,0.f,0.f}, num = {0.f,0.f,0.f,0.f};

    for (int it = 0; it < 32; ++it) {
        f32x16 a_next;
        if (it < 31) {
            // MFMA for tile it+1 issues before exp of tile it (fills matrix pipe)
#pragma unroll
            for (int i = 0; i < 16; i++) a_next[i] = 0.f;
#pragma unroll
            for (int kq = 0; kq < 4; kq++)
                a_next = __builtin_amdgcn_mfma_f32_32x32x16_bf16(p[kq], q[kq], a_next, 0, 0, 0);
            if (it < 30) {
                const unsigned short* pb = phimu + ((it + 2) * 32 + r) * NH + half * 8;
#pragma unroll
                for (int kq = 0; kq < 4; kq++) p[kq] = *(const bf16x8*)(pb + kq * 16);
            }
        }
        // exp + accumulate tile it (overlaps a_next's MFMA execution)
        const int mb = it * 32;
        f32x4 pv[4];
#pragma unroll
        for (int g = 0; g < 4; g++) pv[g] = *(const f32x4*)(s_plus + mb + 4 * half + 8 * g);
#pragma unroll
        for (int reg = 0; reg < 16; reg++) {
            float pl = pv[reg >> 2][reg & 3];  // m = mb + (reg&3) + 8*(reg>>2) + 4*half
            float e = __expf(a_cur[reg]);
            den[reg & 3] += e;
            num[reg & 3] = fmaf(e, pl, num[reg & 3]);
        }
        if (it < 31) a_cur = a_next;
    }
    float d  = (den[0] + den[1]) + (den[2] + den[3]);
    float nu = (num[0] + num[1]) + (num[2] + num[3]);
    // combine the two halves (same b = bstrip + r, different m rows)
    d += __shfl_xor(d, 32); nu += __shfl_xor(nu, 32);
    if (half == 0) { dsum[wv][r] = d; nsum[wv][r] = nu; }
    __syncthreads();

    float bce = 0.f;
    if (t < 128) {
        float dd = dsum[t >> 5][t & 31];
        float nn = nsum[t >> 5][t & 31];
        float p2 = nn / dd;
        p2 = fminf(fmaxf(p2, 1e-6f), 1.0f - 1e-6f);
        float tg = seq[(size_t)(bblk * 128 + t) * NPOS + n];
        bce = (tg > 0.f) ? -logf(p2) : -logf(1.0f - p2);
    }
#pragma unroll
    for (int o = 32; o; o >>= 1) bce += __shfl_xor(bce, o);
    if (t < 128 && lane == 0) wsum[wv] = bce;
    __syncthreads();
    if (t == 0) atomicAdd(accum, wsum[0] + wsum[1]);
}

// ---------------- K4: finalize mean ----------------
__global__ void k4_final(const float* __restrict__ accum, float* __restrict__ out) {
    out[0] = accum[0] * (1.0f / 130816.0f);  // / (B*(N-1))
}

extern "C" void kernel_launch(void* const* d_in, const int* in_sizes, int n_in,
                              void* d_out, int out_size, void* d_ws, size_t ws_size,
                              hipStream_t stream) {
    const float* seq = (const float*)d_in[0];  // (B,N)
    const float* mem = (const float*)d_in[1];  // (M,N)
    const float* Al  = (const float*)d_in[2];  // (N,H,N)
    const float* Bl  = (const float*)d_in[3];  // (H,N)

    char* ws = (char*)d_ws;
    unsigned short* seq_bf = (unsigned short*)(ws + 0);          // 256 KB
    float*          BnT    = (float*)(ws + 262144);              // 128 KB (N,H)
    unsigned short* phimu  = (unsigned short*)(ws + 393216);     // 128 KB (M,H)
    float*          plusT  = (float*)(ws + 524288);              // 2 MB (N,M)
    unsigned short* hatphi = (unsigned short*)(ws + 2621440);    // 16.7 MB (N-1,B,H)
    float*          accum  = (float*)(ws + 19365888);            // 4 B

    k0_seq_bf16<<<128, 256, 0, stream>>>(seq, seq_bf, accum);
    k1a_bnT<<<64, 64, 0, stream>>>(Bl, BnT);
    k1b_phimu<<<1024, 256, 0, stream>>>(BnT, mem, phimu);
    k1c_plusT<<<128, 256, 0, stream>>>(mem, plusT);
    k2_hatphi<<<511, 256, 0, stream>>>(Al, seq_bf, hatphi);
    k3_retrieve<<<dim3(511, 2), 256, 0, stream>>>(hatphi, phimu, plusT, seq, accum);
    k4_final<<<1, 1, 0, stream>>>(accum, (float*)d_out);
}